// Round 5
// baseline (122.714 us; speedup 1.0000x reference)
//
#include <hip/hip_runtime.h>
#include <stdint.h>

#define NN 16384
#define KK 64
#define DD 128
#define PP 8
#define NB 32
#define CH 64
#define MAXCHUNK (NN / CH + NB)   // 288 worst case

typedef unsigned short ushort_t;
typedef __attribute__((ext_vector_type(8))) short short8;
typedef __attribute__((ext_vector_type(4))) float f32x4;

__device__ __forceinline__ ushort_t f2bf(float x) {
    unsigned u = __float_as_uint(x);
    u += 0x7fffu + ((u >> 16) & 1u);     // round-to-nearest-even
    return (ushort_t)(u >> 16);
}
__device__ __forceinline__ float silu_f(float v) { return v / (1.0f + __expf(-v)); }

// ---------------- kA: worklist + weight bf16 conversion + sfT zeroing -------
__global__ void kA_prep(const int* __restrict__ batch,
                        const float* __restrict__ W1, const float* __restrict__ W2,
                        const float* __restrict__ W3, const float* __restrict__ W4,
                        ushort_t* __restrict__ Wb, int4* __restrict__ wl,
                        int* __restrict__ nwl, float* __restrict__ sfT) {
    if (blockIdx.x == 0) {
        __shared__ int starts[NB + 1];
        __shared__ int offs[NB + 1];
        const int t = threadIdx.x;
        if (t <= NB) {
            if (t == NB) {
                starts[NB] = NN;
            } else {
                int lo = 0, hi = NN;
                while (lo < hi) {
                    int mid = (lo + hi) >> 1;
                    if (batch[mid] < t) lo = mid + 1; else hi = mid;
                }
                starts[t] = lo;
            }
        }
        __syncthreads();
        if (t == 0) {
            int off = 0;
            for (int b = 0; b < NB; ++b) {
                offs[b] = off;
                off += (starts[b + 1] - starts[b] + CH - 1) / CH;
            }
            *nwl = off;
        }
        __syncthreads();
        if (t < NB) {
            int s = starts[t], e = starts[t + 1], o = offs[t];
            for (int r = s; r < e; r += CH) {
                int4 en; en.x = t; en.y = r; en.z = min(CH, e - r); en.w = 0;
                wl[o++] = en;
            }
        }
    } else if (blockIdx.x <= 16) {
        int w = blockIdx.x - 1;                 // 0..15
        const float* s = (w >> 2) == 0 ? W1 : (w >> 2) == 1 ? W2 : (w >> 2) == 2 ? W3 : W4;
        int off = (w & 3) * 4096;
        ushort_t* d = Wb + (size_t)(w >> 2) * 16384 + off;
        const float* sp = s + off;
        for (int i = threadIdx.x; i < 4096; i += 256) d[i] = f2bf(sp[i]);
    } else {
        const f32x4 z4 = {0.f, 0.f, 0.f, 0.f};
        f32x4* dst = (f32x4*)sfT + (size_t)(blockIdx.x - 17) * 1024 + threadIdx.x;
#pragma unroll
        for (int q = 0; q < 4; ++q) dst[q * 256] = z4;
    }
}

// ---------------- kB: pre-MLP + residual + LN + trig + transposes -----------
__global__ __launch_bounds__(256, 2) void kB_pre(
        const float* __restrict__ x, const ushort_t* __restrict__ Wb,
        const float* __restrict__ gamma, const float* __restrict__ beta,
        const float* __restrict__ kdr, const float* __restrict__ damp,
        ushort_t* __restrict__ trig_rm, ushort_t* __restrict__ trigT,
        ushort_t* __restrict__ xresT) {
    __shared__ float xf[64][132];
    __shared__ __align__(16) ushort_t xsb[64][136];   // x bf16, later trig tile
    __shared__ __align__(16) ushort_t t1b[64][136];   // t1, later LN(xres) bf16
    const int t = threadIdx.x, lane = t & 63, wv = t >> 6;
    const int n0 = blockIdx.x * 64;
    const ushort_t* W1b = Wb;
    const ushort_t* W2b = Wb + 16384;

    for (int i = t; i < 2048; i += 256) {
        float4 v = ((const float4*)(x + (size_t)n0 * DD))[i];
        int r = i >> 5, c = (i & 31) << 2;
        *(float4*)&xf[r][c] = v;
        xsb[r][c] = f2bf(v.x); xsb[r][c + 1] = f2bf(v.y);
        xsb[r][c + 2] = f2bf(v.z); xsb[r][c + 3] = f2bf(v.w);
    }
    __syncthreads();

    const int ar0 = wv * 16;
    const int fr = (lane >> 4) * 8, cr = lane & 15, rr4 = (lane >> 4) * 4;
    f32x4 acc[8];
    const f32x4 z4 = {0.f, 0.f, 0.f, 0.f};

    // GEMM1: silu(x @ W1^T) -> t1b
#pragma unroll
    for (int nt = 0; nt < 8; ++nt) acc[nt] = z4;
#pragma unroll
    for (int ks = 0; ks < 4; ++ks) {
        short8 af = *(const short8*)&xsb[ar0 + cr][ks * 32 + fr];
#pragma unroll
        for (int nt = 0; nt < 8; ++nt) {
            short8 bf = *(const short8*)&W1b[(size_t)(nt * 16 + cr) * DD + ks * 32 + fr];
            acc[nt] = __builtin_amdgcn_mfma_f32_16x16x32_bf16(af, bf, acc[nt], 0, 0, 0);
        }
    }
#pragma unroll
    for (int nt = 0; nt < 8; ++nt)
#pragma unroll
        for (int r = 0; r < 4; ++r)
            t1b[ar0 + rr4 + r][nt * 16 + cr] = f2bf(silu_f(acc[nt][r]));
    __syncthreads();

    // GEMM2: xf += silu(t1 @ W2^T)
#pragma unroll
    for (int nt = 0; nt < 8; ++nt) acc[nt] = z4;
#pragma unroll
    for (int ks = 0; ks < 4; ++ks) {
        short8 af = *(const short8*)&t1b[ar0 + cr][ks * 32 + fr];
#pragma unroll
        for (int nt = 0; nt < 8; ++nt) {
            short8 bf = *(const short8*)&W2b[(size_t)(nt * 16 + cr) * DD + ks * 32 + fr];
            acc[nt] = __builtin_amdgcn_mfma_f32_16x16x32_bf16(af, bf, acc[nt], 0, 0, 0);
        }
    }
#pragma unroll
    for (int nt = 0; nt < 8; ++nt)
#pragma unroll
        for (int r = 0; r < 4; ++r)
            xf[ar0 + rr4 + r][nt * 16 + cr] += silu_f(acc[nt][r]);
    __syncthreads();

    // phase 3a: LayerNorm rows -> t1b (bf16 xres)
    {
        float g0 = gamma[lane], g1 = gamma[lane + 64];
        float be0 = beta[lane], be1 = beta[lane + 64];
        for (int r = wv; r < 64; r += 4) {
            float a = xf[r][lane], b = xf[r][lane + 64];
            float s = a + b, sq = a * a + b * b;
#pragma unroll
            for (int off = 32; off > 0; off >>= 1) { s += __shfl_xor(s, off); sq += __shfl_xor(sq, off); }
            float mu = s * (1.0f / 128.0f);
            float var = sq * (1.0f / 128.0f) - mu * mu;
            float rs = rsqrtf(var + 1e-5f);
            t1b[r][lane]      = f2bf((a - mu) * rs * g0 + be0);
            t1b[r][lane + 64] = f2bf((b - mu) * rs * g1 + be1);
        }
    }
    // phase 3b: trig -> xsb tile + trig_rm
    for (int i = t; i < 2048; i += 256) {
        int r = i >> 5, kk = (i & 31) * 2;
        float2 kv = *(const float2*)&kdr[(size_t)(n0 + r) * KK + kk];
        float2 dv = *(const float2*)&damp[(size_t)(n0 + r) * KK + kk];
        float s0, c0, s1, c1;
        __sincosf(kv.x, &s0, &c0);
        __sincosf(kv.y, &s1, &c1);
        ushort_t rc0 = f2bf(c0 * dv.x), rc1 = f2bf(c1 * dv.y);
        ushort_t is0 = f2bf(s0 * dv.x), is1 = f2bf(s1 * dv.y);
        xsb[r][kk] = rc0; xsb[r][kk + 1] = rc1;
        xsb[r][64 + kk] = is0; xsb[r][64 + kk + 1] = is1;
        ushort2 a; a.x = rc0; a.y = rc1;
        ushort2 b; b.x = is0; b.y = is1;
        *(ushort2*)&trig_rm[(size_t)(n0 + r) * 128 + kk] = a;
        *(ushort2*)&trig_rm[(size_t)(n0 + r) * 128 + 64 + kk] = b;
    }
    __syncthreads();

    // phase 4: transposed writes
    {
        int m = t >> 1, h = (t & 1) * 32;
#pragma unroll
        for (int q = 0; q < 4; ++q) {
            short8 v;
#pragma unroll
            for (int j = 0; j < 8; ++j) v[j] = (short)xsb[h + q * 8 + j][m];
            *(short8*)&trigT[(size_t)m * NN + n0 + h + q * 8] = v;
        }
#pragma unroll
        for (int q = 0; q < 4; ++q) {
            short8 v;
#pragma unroll
            for (int j = 0; j < 8; ++j) v[j] = (short)t1b[h + q * 8 + j][m];
            *(short8*)&xresT[(size_t)m * NN + n0 + h + q * 8] = v;
        }
    }
}

// ---------------- kC: scatter + kfilter, atomic into sfT f32 ----------------
__global__ __launch_bounds__(256, 3) void kC_scatter(
        const ushort_t* __restrict__ xresT, const ushort_t* __restrict__ trigT,
        const int4* __restrict__ wl, const int* __restrict__ nwl,
        const float* __restrict__ dp, const float* __restrict__ wup,
        float* __restrict__ sfT) {
    __shared__ __align__(16) ushort_t xt[128][88];
    __shared__ __align__(16) ushort_t tt[128][88];
    if (blockIdx.x >= *nwl) return;
    int4 e = wl[blockIdx.x];
    const int b = e.x, r0 = e.y, len = e.z;
    const int t = threadIdx.x, lane = t & 63, wv = t >> 6;

    for (int i = t; i < 512; i += 256) {
        int which = i >> 8, row = (i & 255) >> 1, h = (i & 1) * 32;
        const ushort_t* src = (which ? trigT : xresT) + (size_t)row * NN + r0 + h;
        ushort_t* dst = (which ? &tt[0][0] : &xt[0][0]) + row * 88 + h;
        if (len == CH) {
#pragma unroll
            for (int q = 0; q < 4; ++q) *(short8*)(dst + q * 8) = *(const short8*)(src + q * 8);
        } else {
            for (int j = 0; j < 32; ++j) { int c = h + j; dst[j] = (c < len) ? src[j] : (ushort_t)0; }
        }
    }
    __syncthreads();

    const int fr = (lane >> 4) * 8, cr = lane & 15, rr4 = (lane >> 4) * 4;
    const f32x4 z4 = {0.f, 0.f, 0.f, 0.f};
    f32x4 acc[2][8];
#pragma unroll
    for (int mt = 0; mt < 2; ++mt)
#pragma unroll
        for (int nt = 0; nt < 8; ++nt) acc[mt][nt] = z4;

#pragma unroll
    for (int ks = 0; ks < 2; ++ks) {
        short8 a0 = *(const short8*)&xt[wv * 32 + cr][ks * 32 + fr];
        short8 a1 = *(const short8*)&xt[wv * 32 + 16 + cr][ks * 32 + fr];
#pragma unroll
        for (int nt = 0; nt < 8; ++nt) {
            short8 bf = *(const short8*)&tt[nt * 16 + cr][ks * 32 + fr];
            acc[0][nt] = __builtin_amdgcn_mfma_f32_16x16x32_bf16(a0, bf, acc[0][nt], 0, 0, 0);
            acc[1][nt] = __builtin_amdgcn_mfma_f32_16x16x32_bf16(a1, bf, acc[1][nt], 0, 0, 0);
        }
    }
    // epilogue: apply kfilter(d, m) then atomic-accumulate (linear, so valid per-partial)
    float* dst = sfT + (size_t)b * 128 * 128;
#pragma unroll
    for (int nt = 0; nt < 8; ++nt) {
        int m = nt * 16 + cr;
        int k = m & 63;
        float4 d0 = *(const float4*)&dp[k * PP];
        float4 d1 = *(const float4*)&dp[k * PP + 4];
#pragma unroll
        for (int mt = 0; mt < 2; ++mt)
#pragma unroll
            for (int r = 0; r < 4; ++r) {
                int d = wv * 32 + mt * 16 + rr4 + r;
                float4 w0 = *(const float4*)&wup[d * PP];
                float4 w1 = *(const float4*)&wup[d * PP + 4];
                float kf = d0.x * w0.x + d0.y * w0.y + d0.z * w0.z + d0.w * w0.w
                         + d1.x * w1.x + d1.y * w1.y + d1.z * w1.z + d1.w * w1.w;
                atomicAdd(&dst[d * 128 + m], acc[mt][nt][r] * kf);
            }
    }
}

// ---------------- kD: gather + message + post-MLP + residual -> out ---------
__global__ __launch_bounds__(256, 2) void kD_post(
        const float* __restrict__ x, const ushort_t* __restrict__ trig_rm,
        const float* __restrict__ sfT, const ushort_t* __restrict__ Wb,
        const int4* __restrict__ wl, const int* __restrict__ nwl,
        float* __restrict__ out) {
    __shared__ __align__(16) ushort_t sft[128][136];  // filtered sf, bf16
    __shared__ __align__(16) ushort_t xs[64][136];    // xg bf16
    __shared__ __align__(16) ushort_t t1[64][136];
    if (blockIdx.x >= *nwl) return;
    int4 e = wl[blockIdx.x];
    const int b = e.x, r0 = e.y, len = e.z;
    const int t = threadIdx.x, lane = t & 63, wv = t >> 6;
    const ushort_t* W3b = Wb + 32768;
    const ushort_t* W4b = Wb + 49152;

    // stage sfT (f32, already filtered) -> bf16 LDS
    const float* src = sfT + (size_t)b * 16384;
    for (int i = t; i < 2048; i += 256) {
        int r = i >> 4, c = (i & 15) * 8;
        float4 a = *(const float4*)(src + r * 128 + c);
        float4 bb = *(const float4*)(src + r * 128 + c + 4);
        short8 v;
        v[0] = (short)f2bf(a.x);  v[1] = (short)f2bf(a.y);
        v[2] = (short)f2bf(a.z);  v[3] = (short)f2bf(a.w);
        v[4] = (short)f2bf(bb.x); v[5] = (short)f2bf(bb.y);
        v[6] = (short)f2bf(bb.z); v[7] = (short)f2bf(bb.w);
        *(short8*)&sft[r][c] = v;
    }
    __syncthreads();

    const int fr = (lane >> 4) * 8, cr = lane & 15, rr4 = (lane >> 4) * 4;
    const f32x4 z4 = {0.f, 0.f, 0.f, 0.f};
    f32x4 acc[8];

    // gather: msg(n, d) = sum_m trig_rm[n][m] * sft[d][m]
    int nrow = r0 + wv * 16 + cr;
    if (nrow >= NN) nrow = NN - 1;
#pragma unroll
    for (int nt = 0; nt < 8; ++nt) acc[nt] = z4;
#pragma unroll
    for (int ks = 0; ks < 4; ++ks) {
        short8 af = *(const short8*)&trig_rm[(size_t)nrow * 128 + ks * 32 + fr];
#pragma unroll
        for (int nt = 0; nt < 8; ++nt) {
            short8 bf = *(const short8*)&sft[nt * 16 + cr][ks * 32 + fr];
            acc[nt] = __builtin_amdgcn_mfma_f32_16x16x32_bf16(af, bf, acc[nt], 0, 0, 0);
        }
    }

    // xg = x + msg: keep f32 in regs (same thread owns same (row,col) in GEMM2 output)
    float xk[8][4];
#pragma unroll
    for (int nt = 0; nt < 8; ++nt)
#pragma unroll
        for (int r = 0; r < 4; ++r) {
            int rr = wv * 16 + rr4 + r;
            int row = r0 + rr; if (row >= NN) row = NN - 1;
            float xv = x[(size_t)row * DD + nt * 16 + cr] + acc[nt][r];
            xk[nt][r] = xv;
            xs[rr][nt * 16 + cr] = f2bf(xv);
        }
    __syncthreads();

    const int ar0 = wv * 16;
    // GEMM1: silu(xg @ W3^T) -> t1
#pragma unroll
    for (int nt = 0; nt < 8; ++nt) acc[nt] = z4;
#pragma unroll
    for (int ks = 0; ks < 4; ++ks) {
        short8 af = *(const short8*)&xs[ar0 + cr][ks * 32 + fr];
#pragma unroll
        for (int nt = 0; nt < 8; ++nt) {
            short8 bf = *(const short8*)&W3b[(size_t)(nt * 16 + cr) * DD + ks * 32 + fr];
            acc[nt] = __builtin_amdgcn_mfma_f32_16x16x32_bf16(af, bf, acc[nt], 0, 0, 0);
        }
    }
#pragma unroll
    for (int nt = 0; nt < 8; ++nt)
#pragma unroll
        for (int r = 0; r < 4; ++r)
            t1[ar0 + rr4 + r][nt * 16 + cr] = f2bf(silu_f(acc[nt][r]));
    __syncthreads();

    // GEMM2: out = xg + silu(t1 @ W4^T), masked to len
#pragma unroll
    for (int nt = 0; nt < 8; ++nt) acc[nt] = z4;
#pragma unroll
    for (int ks = 0; ks < 4; ++ks) {
        short8 af = *(const short8*)&t1[ar0 + cr][ks * 32 + fr];
#pragma unroll
        for (int nt = 0; nt < 8; ++nt) {
            short8 bf = *(const short8*)&W4b[(size_t)(nt * 16 + cr) * DD + ks * 32 + fr];
            acc[nt] = __builtin_amdgcn_mfma_f32_16x16x32_bf16(af, bf, acc[nt], 0, 0, 0);
        }
    }
#pragma unroll
    for (int nt = 0; nt < 8; ++nt)
#pragma unroll
        for (int r = 0; r < 4; ++r) {
            int rr = wv * 16 + rr4 + r;
            if (rr < len)
                out[(size_t)(r0 + rr) * DD + nt * 16 + cr] = xk[nt][r] + silu_f(acc[nt][r]);
        }
}

extern "C" void kernel_launch(void* const* d_in, const int* in_sizes, int n_in,
                              void* d_out, int out_size, void* d_ws, size_t ws_size,
                              hipStream_t stream) {
    const float* x      = (const float*)d_in[0];
    const float* kdr    = (const float*)d_in[1];
    const float* damp   = (const float*)d_in[2];
    const int*   batch  = (const int*)d_in[3];
    const float* dp     = (const float*)d_in[4];
    const float* W_pre1 = (const float*)d_in[5];
    const float* W_pre2 = (const float*)d_in[6];
    const float* gamma  = (const float*)d_in[7];
    const float* beta   = (const float*)d_in[8];
    const float* W_up   = (const float*)d_in[9];
    const float* W_upd1 = (const float*)d_in[10];
    const float* W_upd2 = (const float*)d_in[11];
    float* out = (float*)d_out;

    char* w = (char*)d_ws;
    ushort_t* Wb   = (ushort_t*)w;                         // 128 KiB
    int4*     wl   = (int4*)(w + 131072);                  // 8 KiB
    int*      nwl  = (int*)(w + 131072 + 8192);
    size_t o = 131072 + 8192 + 256;
    ushort_t* trig_rm = (ushort_t*)(w + o);  o += (size_t)NN * 128 * 2;      // 4 MB
    ushort_t* trigT   = (ushort_t*)(w + o);  o += (size_t)128 * NN * 2;      // 4 MB
    ushort_t* xresT   = (ushort_t*)(w + o);  o += (size_t)128 * NN * 2;      // 4 MB
    float*    sfT     = (float*)(w + o);     o += (size_t)NB * 128 * 128 * 4; // 2 MB

    hipLaunchKernelGGL(kA_prep, dim3(145), dim3(256), 0, stream,
                       batch, W_pre1, W_pre2, W_upd1, W_upd2, Wb, wl, nwl, sfT);
    hipLaunchKernelGGL(kB_pre, dim3(NN / 64), dim3(256), 0, stream,
                       x, Wb, gamma, beta, kdr, damp, trig_rm, trigT, xresT);
    hipLaunchKernelGGL(kC_scatter, dim3(MAXCHUNK), dim3(256), 0, stream,
                       xresT, trigT, wl, nwl, dp, W_up, sfT);
    hipLaunchKernelGGL(kD_post, dim3(MAXCHUNK), dim3(256), 0, stream,
                       x, trig_rm, sfT, Wb, wl, nwl, out);
}

// Round 6
// 83.925 us; speedup vs baseline: 1.4622x; 1.4622x over previous
//
#include <hip/hip_runtime.h>
#include <stdint.h>

#define NN 16384
#define KK 64
#define DD 128
#define PP 8
#define NB 32
#define CH 64
#define MAXCHUNK (NN / CH + NB)   // 288 worst case

typedef unsigned short ushort_t;
typedef __attribute__((ext_vector_type(8))) short short8;
typedef __attribute__((ext_vector_type(4))) float f32x4;

__device__ __forceinline__ ushort_t f2bf(float x) {
    unsigned u = __float_as_uint(x);
    u += 0x7fffu + ((u >> 16) & 1u);     // round-to-nearest-even
    return (ushort_t)(u >> 16);
}
__device__ __forceinline__ float silu_f(float v) { return v / (1.0f + __expf(-v)); }

// ---------------- kA: worklist + segment starts + weight bf16 conversion ----
__global__ void kA_prep(const int* __restrict__ batch,
                        const float* __restrict__ W1, const float* __restrict__ W2,
                        const float* __restrict__ W3, const float* __restrict__ W4,
                        ushort_t* __restrict__ Wb, int4* __restrict__ wl,
                        int* __restrict__ nwl, int* __restrict__ starts_g) {
    if (blockIdx.x == 0) {
        __shared__ int starts[NB + 1];
        __shared__ int offs[NB + 1];
        const int t = threadIdx.x;
        if (t <= NB) {
            int lo;
            if (t == NB) {
                lo = NN;
            } else {
                lo = 0; int hi = NN;
                while (lo < hi) {
                    int mid = (lo + hi) >> 1;
                    if (batch[mid] < t) lo = mid + 1; else hi = mid;
                }
            }
            starts[t] = lo;
            starts_g[t] = lo;
        }
        __syncthreads();
        if (t == 0) {
            int off = 0;
            for (int b = 0; b < NB; ++b) {
                offs[b] = off;
                off += (starts[b + 1] - starts[b] + CH - 1) / CH;
            }
            *nwl = off;
        }
        __syncthreads();
        if (t < NB) {
            int s = starts[t], e = starts[t + 1], o = offs[t];
            for (int r = s; r < e; r += CH) {
                int4 en; en.x = t; en.y = r; en.z = min(CH, e - r); en.w = 0;
                wl[o++] = en;
            }
        }
    } else {
        int w = blockIdx.x - 1;                 // 0..15
        const float* s = (w >> 2) == 0 ? W1 : (w >> 2) == 1 ? W2 : (w >> 2) == 2 ? W3 : W4;
        int off = (w & 3) * 4096;
        ushort_t* d = Wb + (size_t)(w >> 2) * 16384 + off;
        const float* sp = s + off;
        for (int i = threadIdx.x; i < 4096; i += 256) d[i] = f2bf(sp[i]);
    }
}

// ---------------- kB: pre-MLP + residual + LN + trig + transposes -----------
__global__ __launch_bounds__(256, 2) void kB_pre(
        const float* __restrict__ x, const ushort_t* __restrict__ Wb,
        const float* __restrict__ gamma, const float* __restrict__ beta,
        const float* __restrict__ kdr, const float* __restrict__ damp,
        ushort_t* __restrict__ trig_rm, ushort_t* __restrict__ trigT,
        ushort_t* __restrict__ xresT) {
    __shared__ float xf[64][132];
    __shared__ __align__(16) ushort_t xsb[64][136];   // x bf16, later trig tile
    __shared__ __align__(16) ushort_t t1b[64][136];   // t1, later LN(xres) bf16
    const int t = threadIdx.x, lane = t & 63, wv = t >> 6;
    const int n0 = blockIdx.x * 64;
    const ushort_t* W1b = Wb;
    const ushort_t* W2b = Wb + 16384;

    for (int i = t; i < 2048; i += 256) {
        float4 v = ((const float4*)(x + (size_t)n0 * DD))[i];
        int r = i >> 5, c = (i & 31) << 2;
        *(float4*)&xf[r][c] = v;
        xsb[r][c] = f2bf(v.x); xsb[r][c + 1] = f2bf(v.y);
        xsb[r][c + 2] = f2bf(v.z); xsb[r][c + 3] = f2bf(v.w);
    }
    __syncthreads();

    const int ar0 = wv * 16;
    const int fr = (lane >> 4) * 8, cr = lane & 15, rr4 = (lane >> 4) * 4;
    f32x4 acc[8];
    const f32x4 z4 = {0.f, 0.f, 0.f, 0.f};

    // GEMM1: silu(x @ W1^T) -> t1b
#pragma unroll
    for (int nt = 0; nt < 8; ++nt) acc[nt] = z4;
#pragma unroll
    for (int ks = 0; ks < 4; ++ks) {
        short8 af = *(const short8*)&xsb[ar0 + cr][ks * 32 + fr];
#pragma unroll
        for (int nt = 0; nt < 8; ++nt) {
            short8 bf = *(const short8*)&W1b[(size_t)(nt * 16 + cr) * DD + ks * 32 + fr];
            acc[nt] = __builtin_amdgcn_mfma_f32_16x16x32_bf16(af, bf, acc[nt], 0, 0, 0);
        }
    }
#pragma unroll
    for (int nt = 0; nt < 8; ++nt)
#pragma unroll
        for (int r = 0; r < 4; ++r)
            t1b[ar0 + rr4 + r][nt * 16 + cr] = f2bf(silu_f(acc[nt][r]));
    __syncthreads();

    // GEMM2: xf += silu(t1 @ W2^T)
#pragma unroll
    for (int nt = 0; nt < 8; ++nt) acc[nt] = z4;
#pragma unroll
    for (int ks = 0; ks < 4; ++ks) {
        short8 af = *(const short8*)&t1b[ar0 + cr][ks * 32 + fr];
#pragma unroll
        for (int nt = 0; nt < 8; ++nt) {
            short8 bf = *(const short8*)&W2b[(size_t)(nt * 16 + cr) * DD + ks * 32 + fr];
            acc[nt] = __builtin_amdgcn_mfma_f32_16x16x32_bf16(af, bf, acc[nt], 0, 0, 0);
        }
    }
#pragma unroll
    for (int nt = 0; nt < 8; ++nt)
#pragma unroll
        for (int r = 0; r < 4; ++r)
            xf[ar0 + rr4 + r][nt * 16 + cr] += silu_f(acc[nt][r]);
    __syncthreads();

    // phase 3a: LayerNorm rows -> t1b (bf16 xres)
    {
        float g0 = gamma[lane], g1 = gamma[lane + 64];
        float be0 = beta[lane], be1 = beta[lane + 64];
        for (int r = wv; r < 64; r += 4) {
            float a = xf[r][lane], b = xf[r][lane + 64];
            float s = a + b, sq = a * a + b * b;
#pragma unroll
            for (int off = 32; off > 0; off >>= 1) { s += __shfl_xor(s, off); sq += __shfl_xor(sq, off); }
            float mu = s * (1.0f / 128.0f);
            float var = sq * (1.0f / 128.0f) - mu * mu;
            float rs = rsqrtf(var + 1e-5f);
            t1b[r][lane]      = f2bf((a - mu) * rs * g0 + be0);
            t1b[r][lane + 64] = f2bf((b - mu) * rs * g1 + be1);
        }
    }
    // phase 3b: trig -> xsb tile + trig_rm
    for (int i = t; i < 2048; i += 256) {
        int r = i >> 5, kk = (i & 31) * 2;
        float2 kv = *(const float2*)&kdr[(size_t)(n0 + r) * KK + kk];
        float2 dv = *(const float2*)&damp[(size_t)(n0 + r) * KK + kk];
        float s0, c0, s1, c1;
        __sincosf(kv.x, &s0, &c0);
        __sincosf(kv.y, &s1, &c1);
        ushort_t rc0 = f2bf(c0 * dv.x), rc1 = f2bf(c1 * dv.y);
        ushort_t is0 = f2bf(s0 * dv.x), is1 = f2bf(s1 * dv.y);
        xsb[r][kk] = rc0; xsb[r][kk + 1] = rc1;
        xsb[r][64 + kk] = is0; xsb[r][64 + kk + 1] = is1;
        ushort2 a; a.x = rc0; a.y = rc1;
        ushort2 b; b.x = is0; b.y = is1;
        *(ushort2*)&trig_rm[(size_t)(n0 + r) * 128 + kk] = a;
        *(ushort2*)&trig_rm[(size_t)(n0 + r) * 128 + 64 + kk] = b;
    }
    __syncthreads();

    // phase 4: transposed writes
    {
        int m = t >> 1, h = (t & 1) * 32;
#pragma unroll
        for (int q = 0; q < 4; ++q) {
            short8 v;
#pragma unroll
            for (int j = 0; j < 8; ++j) v[j] = (short)xsb[h + q * 8 + j][m];
            *(short8*)&trigT[(size_t)m * NN + n0 + h + q * 8] = v;
        }
#pragma unroll
        for (int q = 0; q < 4; ++q) {
            short8 v;
#pragma unroll
            for (int j = 0; j < 8; ++j) v[j] = (short)t1b[h + q * 8 + j][m];
            *(short8*)&xresT[(size_t)m * NN + n0 + h + q * 8] = v;
        }
    }
}

// ---------------- kS: per-segment scatter, no atomics -----------------------
// block (b, g): accumulates sf[b, d0..d0+16, 0..128) in registers over all
// chunks of segment b, applies kfilter, writes bf16 SFTb with plain stores.
__global__ __launch_bounds__(256, 2) void kS_scatter(
        const ushort_t* __restrict__ xresT, const ushort_t* __restrict__ trigT,
        const int* __restrict__ starts_g,
        const float* __restrict__ dp, const float* __restrict__ wup,
        ushort_t* __restrict__ SFTb) {
    __shared__ __align__(16) ushort_t xt[16][72];    // 16 d-rows x 64 r
    __shared__ __align__(16) ushort_t tt[128][72];   // 128 m-rows x 64 r
    const int b = blockIdx.x >> 3, g = blockIdx.x & 7, d0 = g * 16;
    const int t = threadIdx.x, lane = t & 63, wv = t >> 6;
    const int start = starts_g[b], end = starts_g[b + 1];

    const int fr = (lane >> 4) * 8, cr = lane & 15, rr4 = (lane >> 4) * 4;
    const f32x4 z4 = {0.f, 0.f, 0.f, 0.f};
    f32x4 acc[2] = {z4, z4};

    for (int r0 = start; r0 < end; r0 += CH) {
        const int len = min(CH, end - r0);
        // stage 144 rows x 64 cols (2 half-rows per index)
        for (int i = t; i < 288; i += 256) {
            int row = i >> 1, h = (i & 1) * 32;
            const ushort_t* src;
            ushort_t* dst;
            if (row < 16) { src = xresT + (size_t)(d0 + row) * NN + r0 + h; dst = &xt[row][h]; }
            else          { src = trigT + (size_t)(row - 16) * NN + r0 + h; dst = &tt[row - 16][h]; }
            if (len == CH) {
#pragma unroll
                for (int q = 0; q < 4; ++q) *(short8*)(dst + q * 8) = *(const short8*)(src + q * 8);
            } else {
                for (int j = 0; j < 32; ++j) { int c = h + j; dst[j] = (c < len) ? src[j] : (ushort_t)0; }
            }
        }
        __syncthreads();
#pragma unroll
        for (int ks = 0; ks < 2; ++ks) {
            short8 af = *(const short8*)&xt[cr][ks * 32 + fr];
#pragma unroll
            for (int j = 0; j < 2; ++j) {
                short8 bf = *(const short8*)&tt[(wv * 2 + j) * 16 + cr][ks * 32 + fr];
                acc[j] = __builtin_amdgcn_mfma_f32_16x16x32_bf16(af, bf, acc[j], 0, 0, 0);
            }
        }
        __syncthreads();
    }

    // epilogue: kfilter(d, m) + bf16 store (plain, no atomics)
    float4 p0[2], p1[2];
#pragma unroll
    for (int j = 0; j < 2; ++j) {
        int m = (wv * 2 + j) * 16 + cr;
        int k = m & 63;
        p0[j] = *(const float4*)&dp[k * PP];
        p1[j] = *(const float4*)&dp[k * PP + 4];
    }
#pragma unroll
    for (int r = 0; r < 4; ++r) {
        int d = d0 + rr4 + r;
        float4 w0 = *(const float4*)&wup[d * PP];
        float4 w1 = *(const float4*)&wup[d * PP + 4];
#pragma unroll
        for (int j = 0; j < 2; ++j) {
            int m = (wv * 2 + j) * 16 + cr;
            float kf = p0[j].x * w0.x + p0[j].y * w0.y + p0[j].z * w0.z + p0[j].w * w0.w
                     + p1[j].x * w1.x + p1[j].y * w1.y + p1[j].z * w1.z + p1[j].w * w1.w;
            SFTb[((size_t)b * 128 + d) * 128 + m] = f2bf(acc[j][r] * kf);
        }
    }
}

// ---------------- kD: gather + message + post-MLP + residual -> out ---------
__global__ __launch_bounds__(256, 2) void kD_post(
        const float* __restrict__ x, const ushort_t* __restrict__ trig_rm,
        const ushort_t* __restrict__ SFTb, const ushort_t* __restrict__ Wb,
        const int4* __restrict__ wl, const int* __restrict__ nwl,
        float* __restrict__ out) {
    __shared__ __align__(16) ushort_t sft[128][136];  // filtered sf, bf16
    __shared__ __align__(16) ushort_t xs[64][136];    // xg bf16
    __shared__ __align__(16) ushort_t t1[64][136];
    if (blockIdx.x >= *nwl) return;
    int4 e = wl[blockIdx.x];
    const int b = e.x, r0 = e.y, len = e.z;
    const int t = threadIdx.x, lane = t & 63, wv = t >> 6;
    const ushort_t* W3b = Wb + 32768;
    const ushort_t* W4b = Wb + 49152;

    // stage SFTb (bf16, already filtered) -> LDS
    const ushort_t* src = SFTb + (size_t)b * 16384;
    for (int i = t; i < 2048; i += 256) {
        int r = i >> 4, c = (i & 15) * 8;
        *(short8*)&sft[r][c] = *(const short8*)(src + r * 128 + c);
    }
    __syncthreads();

    const int fr = (lane >> 4) * 8, cr = lane & 15, rr4 = (lane >> 4) * 4;
    const f32x4 z4 = {0.f, 0.f, 0.f, 0.f};
    f32x4 acc[8];

    // gather: msg(n, d) = sum_m trig_rm[n][m] * sft[d][m]
    int nrow = r0 + wv * 16 + cr;
    if (nrow >= NN) nrow = NN - 1;
#pragma unroll
    for (int nt = 0; nt < 8; ++nt) acc[nt] = z4;
#pragma unroll
    for (int ks = 0; ks < 4; ++ks) {
        short8 af = *(const short8*)&trig_rm[(size_t)nrow * 128 + ks * 32 + fr];
#pragma unroll
        for (int nt = 0; nt < 8; ++nt) {
            short8 bf = *(const short8*)&sft[nt * 16 + cr][ks * 32 + fr];
            acc[nt] = __builtin_amdgcn_mfma_f32_16x16x32_bf16(af, bf, acc[nt], 0, 0, 0);
        }
    }

    // xg = x + msg: keep f32 in regs (same thread owns same (row,col) in GEMM2 output)
    float xk[8][4];
#pragma unroll
    for (int nt = 0; nt < 8; ++nt)
#pragma unroll
        for (int r = 0; r < 4; ++r) {
            int rr = wv * 16 + rr4 + r;
            int row = r0 + rr; if (row >= NN) row = NN - 1;
            float xv = x[(size_t)row * DD + nt * 16 + cr] + acc[nt][r];
            xk[nt][r] = xv;
            xs[rr][nt * 16 + cr] = f2bf(xv);
        }
    __syncthreads();

    const int ar0 = wv * 16;
    // GEMM1: silu(xg @ W3^T) -> t1
#pragma unroll
    for (int nt = 0; nt < 8; ++nt) acc[nt] = z4;
#pragma unroll
    for (int ks = 0; ks < 4; ++ks) {
        short8 af = *(const short8*)&xs[ar0 + cr][ks * 32 + fr];
#pragma unroll
        for (int nt = 0; nt < 8; ++nt) {
            short8 bf = *(const short8*)&W3b[(size_t)(nt * 16 + cr) * DD + ks * 32 + fr];
            acc[nt] = __builtin_amdgcn_mfma_f32_16x16x32_bf16(af, bf, acc[nt], 0, 0, 0);
        }
    }
#pragma unroll
    for (int nt = 0; nt < 8; ++nt)
#pragma unroll
        for (int r = 0; r < 4; ++r)
            t1[ar0 + rr4 + r][nt * 16 + cr] = f2bf(silu_f(acc[nt][r]));
    __syncthreads();

    // GEMM2: out = xg + silu(t1 @ W4^T), masked to len
#pragma unroll
    for (int nt = 0; nt < 8; ++nt) acc[nt] = z4;
#pragma unroll
    for (int ks = 0; ks < 4; ++ks) {
        short8 af = *(const short8*)&t1[ar0 + cr][ks * 32 + fr];
#pragma unroll
        for (int nt = 0; nt < 8; ++nt) {
            short8 bf = *(const short8*)&W4b[(size_t)(nt * 16 + cr) * DD + ks * 32 + fr];
            acc[nt] = __builtin_amdgcn_mfma_f32_16x16x32_bf16(af, bf, acc[nt], 0, 0, 0);
        }
    }
#pragma unroll
    for (int nt = 0; nt < 8; ++nt)
#pragma unroll
        for (int r = 0; r < 4; ++r) {
            int rr = wv * 16 + rr4 + r;
            if (rr < len)
                out[(size_t)(r0 + rr) * DD + nt * 16 + cr] = xk[nt][r] + silu_f(acc[nt][r]);
        }
}

extern "C" void kernel_launch(void* const* d_in, const int* in_sizes, int n_in,
                              void* d_out, int out_size, void* d_ws, size_t ws_size,
                              hipStream_t stream) {
    const float* x      = (const float*)d_in[0];
    const float* kdr    = (const float*)d_in[1];
    const float* damp   = (const float*)d_in[2];
    const int*   batch  = (const int*)d_in[3];
    const float* dp     = (const float*)d_in[4];
    const float* W_pre1 = (const float*)d_in[5];
    const float* W_pre2 = (const float*)d_in[6];
    const float* gamma  = (const float*)d_in[7];
    const float* beta   = (const float*)d_in[8];
    const float* W_up   = (const float*)d_in[9];
    const float* W_upd1 = (const float*)d_in[10];
    const float* W_upd2 = (const float*)d_in[11];
    float* out = (float*)d_out;

    char* w = (char*)d_ws;
    ushort_t* Wb      = (ushort_t*)w;                      // 128 KiB
    int4*     wl      = (int4*)(w + 131072);               // 8 KiB
    int*      nwl     = (int*)(w + 131072 + 8192);
    int*      starts_g= (int*)(w + 131072 + 8192 + 64);    // 33 ints
    size_t o = 131072 + 8192 + 512;
    ushort_t* trig_rm = (ushort_t*)(w + o);  o += (size_t)NN * 128 * 2;      // 4 MB
    ushort_t* trigT   = (ushort_t*)(w + o);  o += (size_t)128 * NN * 2;      // 4 MB
    ushort_t* xresT   = (ushort_t*)(w + o);  o += (size_t)128 * NN * 2;      // 4 MB
    ushort_t* SFTb    = (ushort_t*)(w + o);  o += (size_t)NB * 128 * 128 * 2; // 1 MB

    hipLaunchKernelGGL(kA_prep, dim3(17), dim3(256), 0, stream,
                       batch, W_pre1, W_pre2, W_upd1, W_upd2, Wb, wl, nwl, starts_g);
    hipLaunchKernelGGL(kB_pre, dim3(NN / 64), dim3(256), 0, stream,
                       x, Wb, gamma, beta, kdr, damp, trig_rm, trigT, xresT);
    hipLaunchKernelGGL(kS_scatter, dim3(NB * 8), dim3(256), 0, stream,
                       xresT, trigT, starts_g, dp, W_up, SFTb);
    hipLaunchKernelGGL(kD_post, dim3(MAXCHUNK), dim3(256), 0, stream,
                       x, trig_rm, SFTb, Wb, wl, nwl, out);
}